// Round 10
// baseline (119.177 us; speedup 1.0000x reference)
//
#include <hip/hip_runtime.h>
#include <hip/hip_bf16.h>
#include <hip/hip_cooperative_groups.h>

#define RTOT 49152
#define RT9  442368               // (RTOT/8) * 72, V-interleaved per-head stride
#define EPSF 1e-5f
#define SCQ 0.5101062398836783f   // (1/sqrt(8)) * log2(e)

typedef _Float16 h2 __attribute__((ext_vector_type(2)));
typedef _Float16 half8 __attribute__((ext_vector_type(8)));
typedef float f32x16 __attribute__((ext_vector_type(16)));

__device__ __forceinline__ h2 cvt2h(float a, float b) {
    return __builtin_bit_cast(h2, __builtin_amdgcn_cvt_pkrtz(a, b));
}
__device__ __forceinline__ unsigned int bcu(h2 v) { return __builtin_bit_cast(unsigned int, v); }

__device__ __forceinline__ void swap32(unsigned int& x, unsigned int& y, int hi) {
#if __has_builtin(__builtin_amdgcn_permlane32_swap)
    auto r = __builtin_amdgcn_permlane32_swap(x, y, false, false);
    x = r[0]; y = r[1];
#else
    unsigned int xs = (unsigned int)__shfl_xor((int)x, 32, 64);
    unsigned int ys = (unsigned int)__shfl_xor((int)y, 32, 64);
    unsigned int nx = hi ? ys : x;
    unsigned int ny = hi ? y : xs;
    x = nx; y = ny;
#endif
}

// ---------------------------------------------------------------------------
// QKV projection (regular launch, proven R8), grid (192, 3): y=0/1/2 -> Q/K/V.
// Raw head-major Y[h][row][8] f16 + mask table zt + stats (LDS reduce ->
// 128 global atomics/block). Fragment layout (verified R4-R8):
// A/B lane&31 = M/N idx, lane>>5 = k-half; D row=(r&3)+8(r>>2)+4hi, col=lane&31.
// ---------------------------------------------------------------------------
__global__ __launch_bounds__(256) void gemm_qkv(
        const float* __restrict__ Qin, const float* __restrict__ Kin,
        const float* __restrict__ mask,
        const float* __restrict__ Wq, const float* __restrict__ bq,
        const float* __restrict__ Wk, const float* __restrict__ bk,
        const float* __restrict__ Wv, const float* __restrict__ bv,
        _Float16* __restrict__ Yq, _Float16* __restrict__ Yk,
        _Float16* __restrict__ Yv, _Float16* __restrict__ zt,
        float* __restrict__ stats) {
    __shared__ char WT[8192];
    __shared__ float red[128];
    int tid = threadIdx.x;
    int which = blockIdx.y;
    const float* X    = which ? Kin : Qin;
    const float* W    = which == 0 ? Wq : (which == 1 ? Wk : Wv);
    const float* bias = which == 0 ? bq : (which == 1 ? bk : bv);
    _Float16* Y       = which == 0 ? Yq : (which == 1 ? Yk : Yv);
    float* st = stats + which * 128;

    for (int i = tid; i < 4096; i += 256) {
        int d = i >> 6, e = i & 63;
        int off = ((e * 64 + d) * 2) ^ ((e & 7) << 4);
        *(_Float16*)(&WT[off]) = (_Float16)W[i];
    }
    if (tid < 128) red[tid] = 0.f;

    int wvi = tid >> 6, lane = tid & 63, ln = lane & 31, hi = lane >> 5;
    int rbase = blockIdx.x * 256 + wvi * 64;

    half8 af[2][4];
#pragma unroll
    for (int rt = 0; rt < 2; rt++)
#pragma unroll
        for (int kc = 0; kc < 4; kc++) {
            const float4* p = (const float4*)(X + (size_t)(rbase + rt*32 + ln) * 64 + kc*16 + 8*hi);
            float4 x = p[0], y = p[1];
            uint4 u = make_uint4(bcu(cvt2h(x.x, x.y)), bcu(cvt2h(x.z, x.w)),
                                 bcu(cvt2h(y.x, y.y)), bcu(cvt2h(y.z, y.w)));
            af[rt][kc] = __builtin_bit_cast(half8, u);
        }

    // mask row-sum table (Q blocks only): zt[h][row] in {0, SCQ}
    if (which == 0) {
        int row = blockIdx.x * 256 + tid;
        const float4* mr = (const float4*)(mask + (size_t)row * 64);
        float s[8];
#pragma unroll
        for (int h8 = 0; h8 < 8; h8++) s[h8] = 0.f;
#pragma unroll
        for (int i = 0; i < 16; i++) {
            float4 m = mr[i];
            s[i >> 1] += m.x + m.y + m.z + m.w;
        }
#pragma unroll
        for (int h8 = 0; h8 < 8; h8++)
            zt[(size_t)h8 * RTOT + row] = (_Float16)((s[h8] == 0.f) ? 0.f : SCQ);
    }
    __syncthreads();

    half8 bf[2][4];
#pragma unroll
    for (int ct = 0; ct < 2; ct++)
#pragma unroll
        for (int kc = 0; kc < 4; kc++) {
            int e = ct * 32 + ln;
            int off = ((e * 64 + kc * 16 + 8 * hi) * 2) ^ ((e & 7) << 4);
            bf[ct][kc] = *(const half8*)(&WT[off]);
        }

    f32x16 acc[2][2];
#pragma unroll
    for (int rt = 0; rt < 2; rt++)
#pragma unroll
        for (int ct = 0; ct < 2; ct++) {
#pragma unroll
            for (int r = 0; r < 16; r++) acc[rt][ct][r] = 0.f;
#pragma unroll
            for (int kc = 0; kc < 4; kc++)
                acc[rt][ct] = __builtin_amdgcn_mfma_f32_32x32x16_f16(
                    af[rt][kc], bf[ct][kc], acc[rt][ct], 0, 0, 0);
        }

#pragma unroll
    for (int ct = 0; ct < 2; ct++) {
        int cc = ct * 32 + ln;
        float bv_ = bias[cc];
        _Float16* Yh = Y + (size_t)(cc >> 3) * RTOT * 8 + (cc & 7);
        float s = 0.f, q = 0.f;
#pragma unroll
        for (int rt = 0; rt < 2; rt++)
#pragma unroll
            for (int r = 0; r < 16; r++) {
                float v = acc[rt][ct][r] + bv_;
                s += v; q += v * v;
                int row = rbase + rt*32 + (r & 3) + 8*(r >> 2) + 4*hi;
                Yh[(size_t)row * 8] = (_Float16)v;
            }
        s += __shfl_xor(s, 32, 64);
        q += __shfl_xor(q, 32, 64);
        if (lane < 32) {
            atomicAdd(&red[cc], s);
            atomicAdd(&red[64 + cc], q);
        }
    }
    __syncthreads();
    if (tid < 128) atomicAdd(&st[tid], red[tid]);
}

// ---------------------------------------------------------------------------
// Streaming BN transform: raw Yq/Yk/Yv (+complete stats) -> fully transformed
// Qt (relu * zm), Kt (relu), Vt ([h][chunk][9][8], col 8 = ones).
// 384 blocks x 256 thr, 128 rows x 8 heads x 3 tensors per block.
// ---------------------------------------------------------------------------
__global__ __launch_bounds__(256) void transform_qkv(
        const _Float16* __restrict__ Yq, const _Float16* __restrict__ Yk,
        const _Float16* __restrict__ Yv, const _Float16* __restrict__ zt,
        const float* __restrict__ stats,
        const float* __restrict__ gq, const float* __restrict__ betaq,
        const float* __restrict__ gk, const float* __restrict__ betak,
        const float* __restrict__ gv, const float* __restrict__ betav,
        _Float16* __restrict__ Qt, _Float16* __restrict__ Kt,
        _Float16* __restrict__ Vt) {
    __shared__ float CF[384];
    int tid = threadIdx.x;
    if (tid < 192) {
        int s = tid >> 6, c = tid & 63;
        const float* g  = s == 0 ? gq : (s == 1 ? gk : gv);
        const float* be = s == 0 ? betaq : (s == 1 ? betak : betav);
        const float* stp = stats + s * 128;
        float inv = 1.f / (float)RTOT;
        float mean = stp[c] * inv;
        float var  = stp[64 + c] * inv - mean * mean;
        float a = g[c] * rsqrtf(var + EPSF);
        CF[s * 128 + c] = a;
        CF[s * 128 + 64 + c] = be[c] - mean * a;
    }
    __syncthreads();

    int rb = blockIdx.x * 128;
    for (int i = tid; i < 1024; i += 256) {
        int h = i >> 7, r = rb + (i & 127);
        size_t idx = ((size_t)h * RTOT + r) * 8;
        half8 yq = *(const half8*)(Yq + idx);
        half8 yk = *(const half8*)(Yk + idx);
        half8 yv = *(const half8*)(Yv + idx);
        float zm = (float)zt[(size_t)h * RTOT + r];
        half8 qv, kv;
        _Float16* vb = Vt + (size_t)h * RT9 + (size_t)(r >> 3) * 72 + (r & 7);
#pragma unroll
        for (int c = 0; c < 8; c++) {
            int cc = h * 8 + c;
            qv[c] = (_Float16)(fmaxf(CF[cc] * (float)yq[c] + CF[64 + cc], 0.f) * zm);
            kv[c] = (_Float16)fmaxf(CF[128 + cc] * (float)yk[c] + CF[192 + cc], 0.f);
            vb[c * 8] = (_Float16)fmaxf(CF[256 + cc] * (float)yv[c] + CF[320 + cc], 0.f);
        }
        *(half8*)(Qt + idx) = qv;
        *(half8*)(Kt + idx) = kv;
    }
    // ones column (c = 8): 16 chunks x 8 heads for this block's 128 rows
    if (tid < 128) {
        int h = tid >> 4, ch = (rb >> 3) + (tid & 15);
        half8 one8;
#pragma unroll
        for (int i = 0; i < 8; i++) one8[i] = (_Float16)1.0f;
        *(half8*)(Vt + (size_t)h * RT9 + (size_t)ch * 72 + 64) = one8;
    }
}

// ---------------------------------------------------------------------------
// MFMA attention, pure copy + MFMA (all BN/mask pre-applied). 512 thr / 8
// waves; grid 1536: p = bid mod 768, half = bid/768 (pair-mates same XCD).
// One 32-row query strip per wave.
// ---------------------------------------------------------------------------
__global__ __launch_bounds__(512) void attn_mfma(
        const _Float16* __restrict__ Qt, const _Float16* __restrict__ Kt,
        const _Float16* __restrict__ Vt, _Float16* __restrict__ O) {
    __shared__ __align__(16) _Float16 KL[4096];   // 8 KB [m][8]
    __shared__ __align__(16) _Float16 VS[4608];   // 9 KB [m/8][9][8]

    int bid = blockIdx.x;
    int p = (bid < 768) ? bid : bid - 768;
    int half_ = (bid < 768) ? 0 : 1;
    int h = p / 96;              // B*T = 96
    int bt = p - h * 96;
    int row0 = bt * 512;
    int tid = threadIdx.x;

    const _Float16* Kth = Kt + (size_t)h * RTOT * 8 + (size_t)row0 * 8;
    const _Float16* Vth = Vt + (size_t)h * RT9 + (size_t)(row0 >> 3) * 72;
    const _Float16* Qth = Qt + (size_t)h * RTOT * 8 + (size_t)row0 * 8;

    ((uint4*)KL)[tid] = ((const uint4*)Kth)[tid];
    for (int i = tid; i < 576; i += 512)
        ((uint4*)VS)[i] = ((const uint4*)Vth)[i];
    __syncthreads();

    int wv = tid >> 6;           // 0..7
    int lane = tid & 63;
    int ln = lane & 31;
    int hi = lane >> 5;

    f32x16 zacc, m12;
#pragma unroll
    for (int r = 0; r < 16; r++) { zacc[r] = 0.f; m12[r] = -12.f; }
    half8 hzero;
#pragma unroll
    for (int i = 0; i < 8; i++) hzero[i] = (_Float16)0.f;

    {
        int si = half_ * 8 + wv;
        int n0 = si * 32;
        half8 qf = hzero;
        if (!hi) qf = *(const half8*)(Qth + (n0 + ln) * 8);
        f32x16 acc = zacc;

#pragma unroll 4
        for (int t = 0; t < 16; t++) {
            half8 kf = hzero;
            if (!hi) kf = *(const half8*)&KL[(t * 32 + ln) * 8];
            f32x16 sv = __builtin_amdgcn_mfma_f32_32x32x16_f16(kf, qf, m12, 0, 0, 0);
            float pe[16];
#pragma unroll
            for (int r = 0; r < 16; r++)
                pe[r] = __builtin_amdgcn_exp2f(sv[r]);
#pragma unroll
            for (int ks = 0; ks < 2; ks++) {
                unsigned int x1 = bcu(cvt2h(pe[8*ks+0], pe[8*ks+1]));
                unsigned int x2 = bcu(cvt2h(pe[8*ks+2], pe[8*ks+3]));
                unsigned int y1 = bcu(cvt2h(pe[8*ks+4], pe[8*ks+5]));
                unsigned int y2 = bcu(cvt2h(pe[8*ks+6], pe[8*ks+7]));
                swap32(x1, y1, hi);
                swap32(x2, y2, hi);
                uint4 pw = make_uint4(x1, x2, y1, y2);
                half8 pa = __builtin_bit_cast(half8, pw);
                int chunk = t * 4 + ks * 2 + hi;
                half8 vf = hzero;
                if (ln <= 8) vf = *(const half8*)&VS[chunk * 72 + ln * 8];
                acc = __builtin_amdgcn_mfma_f32_32x32x16_f16(pa, vf, acc, 0, 0, 0);
            }
        }

        _Float16* Oh = O + (size_t)h * RTOT * 8 + (size_t)row0 * 8;
#pragma unroll
        for (int r = 0; r < 16; r++) {
            float av = acc[r];
            float den = __shfl(av, 8 + 32 * hi, 64);
            float ov = av * __builtin_amdgcn_rcpf(den);
            if (ln < 8) {
                int nrow = n0 + (r & 3) + 8 * (r >> 2) + 4 * hi;
                Oh[nrow * 8 + ln] = (_Float16)ov;
            }
        }
    }
}

// ---------------------------------------------------------------------------
// Cooperative (192 blocks, proven R7/R8): O-projection GEMM (head-major X) +
// stats + grid.sync + BN-ReLU -> d_out. Accumulators live across the sync.
// ---------------------------------------------------------------------------
__global__ __launch_bounds__(256) void gemm_o_norm(
        const _Float16* __restrict__ X,
        const float* __restrict__ Wo, const float* __restrict__ bo,
        const float* __restrict__ go, const float* __restrict__ betao,
        float* __restrict__ st, float* __restrict__ out) {
    __shared__ char WT[8192];
    __shared__ float red[128];
    __shared__ float CF[128];
    int tid = threadIdx.x;
    for (int i = tid; i < 4096; i += 256) {
        int d = i >> 6, e = i & 63;
        int off = ((e * 64 + d) * 2) ^ ((e & 7) << 4);
        *(_Float16*)(&WT[off]) = (_Float16)Wo[i];
    }
    if (tid < 128) red[tid] = 0.f;

    int wvi = tid >> 6, lane = tid & 63, ln = lane & 31, hi = lane >> 5;
    int rbase = blockIdx.x * 256 + wvi * 64;

    half8 af[2][4];
#pragma unroll
    for (int rt = 0; rt < 2; rt++)
#pragma unroll
        for (int kc = 0; kc < 4; kc++)
            af[rt][kc] = *(const half8*)(X + ((size_t)(2*kc + hi) * RTOT + rbase + rt*32 + ln) * 8);
    __syncthreads();

    half8 bf[2][4];
#pragma unroll
    for (int ct = 0; ct < 2; ct++)
#pragma unroll
        for (int kc = 0; kc < 4; kc++) {
            int e = ct * 32 + ln;
            int off = ((e * 64 + kc * 16 + 8 * hi) * 2) ^ ((e & 7) << 4);
            bf[ct][kc] = *(const half8*)(&WT[off]);
        }

    f32x16 acc[2][2];
#pragma unroll
    for (int rt = 0; rt < 2; rt++)
#pragma unroll
        for (int ct = 0; ct < 2; ct++) {
#pragma unroll
            for (int r = 0; r < 16; r++) acc[rt][ct][r] = 0.f;
#pragma unroll
            for (int kc = 0; kc < 4; kc++)
                acc[rt][ct] = __builtin_amdgcn_mfma_f32_32x32x16_f16(
                    af[rt][kc], bf[ct][kc], acc[rt][ct], 0, 0, 0);
        }

#pragma unroll
    for (int ct = 0; ct < 2; ct++) {
        float bv_ = bo[ct * 32 + ln];
        float s = 0.f, q = 0.f;
#pragma unroll
        for (int rt = 0; rt < 2; rt++)
#pragma unroll
            for (int r = 0; r < 16; r++) {
                float v = acc[rt][ct][r] + bv_;
                acc[rt][ct][r] = v;
                s += v; q += v * v;
            }
        s += __shfl_xor(s, 32, 64);
        q += __shfl_xor(q, 32, 64);
        if (lane < 32) {
            atomicAdd(&red[ct*32 + ln], s);
            atomicAdd(&red[64 + ct*32 + ln], q);
        }
    }
    __syncthreads();
    if (tid < 128) atomicAdd(&st[tid], red[tid]);

    __threadfence();
    cooperative_groups::this_grid().sync();

    if (tid < 64) {
        float inv = 1.f / (float)RTOT;
        float mean = st[tid] * inv;
        float var  = st[64 + tid] * inv - mean * mean;
        float a = go[tid] * rsqrtf(var + EPSF);
        CF[tid] = a;
        CF[64 + tid] = betao[tid] - mean * a;
    }
    __syncthreads();

#pragma unroll
    for (int ct = 0; ct < 2; ct++) {
        int c = ct * 32 + ln;
        float a = CF[c], b = CF[64 + c];
#pragma unroll
        for (int rt = 0; rt < 2; rt++)
#pragma unroll
            for (int r = 0; r < 16; r++) {
                int row = rbase + rt*32 + (r & 3) + 8*(r >> 2) + 4*hi;
                out[(size_t)row * 64 + c] = fmaxf(a * acc[rt][ct][r] + b, 0.f);
            }
    }
}

extern "C" void kernel_launch(void* const* d_in, const int* in_sizes, int n_in,
                              void* d_out, int out_size, void* d_ws, size_t ws_size,
                              hipStream_t stream) {
    const float* Q    = (const float*)d_in[0];
    const float* Kin  = (const float*)d_in[1];
    const float* mask = (const float*)d_in[2];
    const float* Wq = (const float*)d_in[4];
    const float* bq = (const float*)d_in[5];
    const float* gq = (const float*)d_in[6];
    const float* betaq = (const float*)d_in[7];
    const float* Wk = (const float*)d_in[8];
    const float* bk = (const float*)d_in[9];
    const float* gk = (const float*)d_in[10];
    const float* betak = (const float*)d_in[11];
    const float* Wv = (const float*)d_in[12];
    const float* bv = (const float*)d_in[13];
    const float* gv = (const float*)d_in[14];
    const float* betav = (const float*)d_in[15];
    const float* Wo = (const float*)d_in[16];
    const float* bo = (const float*)d_in[17];
    const float* go = (const float*)d_in[18];
    const float* betao = (const float*)d_in[19];

    const size_t TSZ = (size_t)RTOT * 64;        // elements per [h][row][8] f16 tensor
    _Float16* Yq = (_Float16*)d_ws;               // raw projections
    _Float16* Yk = Yq + TSZ;
    _Float16* Yv = Yk + TSZ;
    _Float16* Qt = Yv + TSZ;                      // transformed
    _Float16* Kt = Qt + TSZ;
    _Float16* Vt = Kt + TSZ;                      // RTOT*72 halfs
    _Float16* Ob = Vt + (size_t)RTOT * 72;
    _Float16* zt = Ob + TSZ;                      // 8 * RTOT halfs
    float* stats = (float*)(zt + (size_t)8 * RTOT);  // 512 floats

    (void)hipMemsetAsync(stats, 0, 512 * sizeof(float), stream);

    dim3 gqkv(192, 3);
    gemm_qkv<<<gqkv, 256, 0, stream>>>(Q, Kin, mask, Wq, bq, Wk, bk, Wv, bv,
                                       Yq, Yk, Yv, zt, stats);

    transform_qkv<<<384, 256, 0, stream>>>(Yq, Yk, Yv, zt, stats,
                                           gq, betaq, gk, betak, gv, betav,
                                           Qt, Kt, Vt);

    attn_mfma<<<1536, 512, 0, stream>>>(Qt, Kt, Vt, Ob);

    {
        const _Float16* Xo = Ob;
        float* st4 = stats + 384;
        float* outp = (float*)d_out;
        void* args[] = { (void*)&Xo, (void*)&Wo, (void*)&bo,
                         (void*)&go, (void*)&betao, (void*)&st4, (void*)&outp };
        (void)hipLaunchCooperativeKernel(reinterpret_cast<void*>(&gemm_o_norm),
                                         dim3(192), dim3(256), args, 0, stream);
    }
}

// Round 12
// 113.716 us; speedup vs baseline: 1.0480x; 1.0480x over previous
//
#include <hip/hip_runtime.h>
#include <hip/hip_bf16.h>
#include <hip/hip_cooperative_groups.h>

#define RTOT 49152
#define RT9  442368               // (RTOT/8) * 72, V-interleaved per-head stride
#define EPSF 1e-5f
#define SCQ 0.5101062398836783f   // (1/sqrt(8)) * log2(e)

typedef _Float16 h2 __attribute__((ext_vector_type(2)));
typedef _Float16 half8 __attribute__((ext_vector_type(8)));
typedef float f32x16 __attribute__((ext_vector_type(16)));

__device__ __forceinline__ h2 cvt2h(float a, float b) {
    return __builtin_bit_cast(h2, __builtin_amdgcn_cvt_pkrtz(a, b));
}
__device__ __forceinline__ unsigned int bcu(h2 v) { return __builtin_bit_cast(unsigned int, v); }

__device__ __forceinline__ void swap32(unsigned int& x, unsigned int& y, int hi) {
#if __has_builtin(__builtin_amdgcn_permlane32_swap)
    auto r = __builtin_amdgcn_permlane32_swap(x, y, false, false);
    x = r[0]; y = r[1];
#else
    unsigned int xs = (unsigned int)__shfl_xor((int)x, 32, 64);
    unsigned int ys = (unsigned int)__shfl_xor((int)y, 32, 64);
    unsigned int nx = hi ? ys : x;
    unsigned int ny = hi ? y : xs;
    x = nx; y = ny;
#endif
}

// ---------------------------------------------------------------------------
// QKV projection, grid (192,3): y = 0/1/2 -> Q/K/V. Raw (pre-BN) f16 outputs,
// stored COALESCED via LDS transpose YT[256][72] (stride 72 f16 = 144 B keeps
// uint4 alignment; 8-way-conflict LDS reads are ~300 cyc/block, negligible):
//   Q/K: head-major [h][row][8], 16B/lane stores.
//   V:   pre-interleaved [h][chunk][9][8] + ones column (c=8).
// Also: mask table zt[h][row] in {0,SCQ}; BN stats via LDS reduce -> 128
// global atomics/block. Fragment layout (verified R4-R10).
// ---------------------------------------------------------------------------
__global__ __launch_bounds__(256) void gemm_qkv(
        const float* __restrict__ Qin, const float* __restrict__ Kin,
        const float* __restrict__ mask,
        const float* __restrict__ Wq, const float* __restrict__ bq,
        const float* __restrict__ Wk, const float* __restrict__ bk,
        const float* __restrict__ Wv, const float* __restrict__ bv,
        _Float16* __restrict__ Yq, _Float16* __restrict__ Yk,
        _Float16* __restrict__ Vr, _Float16* __restrict__ zt,
        float* __restrict__ stats) {
    __shared__ char WT[8192];
    __shared__ _Float16 YT[256 * 72];
    __shared__ float red[128];
    int tid = threadIdx.x;
    int which = blockIdx.y;
    const float* X    = which ? Kin : Qin;
    const float* W    = which == 0 ? Wq : (which == 1 ? Wk : Wv);
    const float* bias = which == 0 ? bq : (which == 1 ? bk : bv);
    float* st = stats + which * 128;

    for (int i = tid; i < 4096; i += 256) {
        int d = i >> 6, e = i & 63;
        int off = ((e * 64 + d) * 2) ^ ((e & 7) << 4);
        *(_Float16*)(&WT[off]) = (_Float16)W[i];
    }
    if (tid < 128) red[tid] = 0.f;

    int wvi = tid >> 6, lane = tid & 63, ln = lane & 31, hi = lane >> 5;
    int rbase = blockIdx.x * 256 + wvi * 64;

    half8 af[2][4];
#pragma unroll
    for (int rt = 0; rt < 2; rt++)
#pragma unroll
        for (int kc = 0; kc < 4; kc++) {
            const float4* p = (const float4*)(X + (size_t)(rbase + rt*32 + ln) * 64 + kc*16 + 8*hi);
            float4 x = p[0], y = p[1];
            uint4 u = make_uint4(bcu(cvt2h(x.x, x.y)), bcu(cvt2h(x.z, x.w)),
                                 bcu(cvt2h(y.x, y.y)), bcu(cvt2h(y.z, y.w)));
            af[rt][kc] = __builtin_bit_cast(half8, u);
        }

    if (which == 0) {   // mask row-sum table, coalesced global writes
        int row = blockIdx.x * 256 + tid;
        const float4* mr = (const float4*)(mask + (size_t)row * 64);
        float s[8];
#pragma unroll
        for (int h8 = 0; h8 < 8; h8++) s[h8] = 0.f;
#pragma unroll
        for (int i = 0; i < 16; i++) {
            float4 m = mr[i];
            s[i >> 1] += m.x + m.y + m.z + m.w;
        }
#pragma unroll
        for (int h8 = 0; h8 < 8; h8++)
            zt[(size_t)h8 * RTOT + row] = (_Float16)((s[h8] == 0.f) ? 0.f : SCQ);
    }
    __syncthreads();

    half8 bf[2][4];
#pragma unroll
    for (int ct = 0; ct < 2; ct++)
#pragma unroll
        for (int kc = 0; kc < 4; kc++) {
            int e = ct * 32 + ln;
            int off = ((e * 64 + kc * 16 + 8 * hi) * 2) ^ ((e & 7) << 4);
            bf[ct][kc] = *(const half8*)(&WT[off]);
        }

    f32x16 acc[2][2];
#pragma unroll
    for (int rt = 0; rt < 2; rt++)
#pragma unroll
        for (int ct = 0; ct < 2; ct++) {
#pragma unroll
            for (int r = 0; r < 16; r++) acc[rt][ct][r] = 0.f;
#pragma unroll
            for (int kc = 0; kc < 4; kc++)
                acc[rt][ct] = __builtin_amdgcn_mfma_f32_32x32x16_f16(
                    af[rt][kc], bf[ct][kc], acc[rt][ct], 0, 0, 0);
        }

    // bias + stats partials; Y into LDS transpose buffer
#pragma unroll
    for (int ct = 0; ct < 2; ct++) {
        int cc = ct * 32 + ln;
        float bv_ = bias[cc];
        float s = 0.f, q = 0.f;
#pragma unroll
        for (int rt = 0; rt < 2; rt++)
#pragma unroll
            for (int r = 0; r < 16; r++) {
                float v = acc[rt][ct][r] + bv_;
                s += v; q += v * v;
                int lrow = wvi*64 + rt*32 + (r & 3) + 8*(r >> 2) + 4*hi;
                YT[lrow * 72 + cc] = (_Float16)v;
            }
        s += __shfl_xor(s, 32, 64);
        q += __shfl_xor(q, 32, 64);
        if (lane < 32) {
            atomicAdd(&red[cc], s);
            atomicAdd(&red[64 + cc], q);
        }
    }
    __syncthreads();
    if (tid < 128) atomicAdd(&st[tid], red[tid]);

    // coalesced store phase
    if (which < 2) {
        _Float16* Y = which == 0 ? Yq : Yk;
#pragma unroll
        for (int j = 0; j < 8; j++) {
            int h = j, r = tid;                // idx = j*256+tid, h = idx>>8
            half8 v = *(const half8*)&YT[r * 72 + h * 8];
            *(half8*)(Y + ((size_t)h * RTOT + blockIdx.x * 256 + r) * 8) = v;
        }
    } else {
        int chBase = blockIdx.x * 32;
#pragma unroll
        for (int j = 0; j < 8; j++) {
            int idx = j * 256 + tid;
            int h = idx >> 8, rem = idx & 255;
            int ch = rem >> 3, c = rem & 7;
            half8 w;
#pragma unroll
            for (int i = 0; i < 8; i++)
                w[i] = YT[(ch * 8 + i) * 72 + h * 8 + c];
            *(half8*)(Vr + (size_t)h * RT9 + (size_t)(chBase + ch) * 72 + c * 8) = w;
        }
        // ones column (c = 8)
        {
            int h = tid >> 5, ch = tid & 31;
            half8 one8;
#pragma unroll
            for (int i = 0; i < 8; i++) one8[i] = (_Float16)1.0f;
            *(half8*)(Vr + (size_t)h * RT9 + (size_t)(chBase + ch) * 72 + 64) = one8;
        }
    }
}

// ---------------------------------------------------------------------------
// MFMA attention, 768 blocks x 512 thr (8 waves, 2 strips/wave): staging+BN
// done ONCE per (head, bt). K: head-major raw -> BN -> KL row-major.
// V: pre-interleaved raw -> per-uint4 BN (c = idx%9; c==8 ones pass-through).
// Q: per-strip from raw head-major, BN * zt. O staged in LDS -> coalesced
// uint4 stores. Softmax shift -12 in MFMA C operand; V col 8 = denominator.
// ---------------------------------------------------------------------------
__global__ __launch_bounds__(512) void attn_mfma(
        const _Float16* __restrict__ Yq, const _Float16* __restrict__ Yk,
        const _Float16* __restrict__ Vr, const _Float16* __restrict__ zt,
        const float* __restrict__ stats,
        const float* __restrict__ gq, const float* __restrict__ betaq,
        const float* __restrict__ gk, const float* __restrict__ betak,
        const float* __restrict__ gv, const float* __restrict__ betav,
        _Float16* __restrict__ O) {
    __shared__ __align__(16) _Float16 KL[4096];   // 8 KB [m][8]
    __shared__ __align__(16) _Float16 VS[4608];   // 9 KB [m/8][9][8]
    __shared__ __align__(16) _Float16 OL[4096];   // 8 KB [row][8]
    __shared__ float CF[384];

    int p = blockIdx.x;
    int h = p / 96;              // B*T = 96
    int bt = p - h * 96;
    int row0 = bt * 512;
    int co = h * 8;
    int tid = threadIdx.x;

    if (tid < 192) {
        int s = tid >> 6, c = tid & 63;
        const float* g  = s == 0 ? gq : (s == 1 ? gk : gv);
        const float* be = s == 0 ? betaq : (s == 1 ? betak : betav);
        const float* stp = stats + s * 128;
        float inv = 1.f / (float)RTOT;
        float mean = stp[c] * inv;
        float var  = stp[64 + c] * inv - mean * mean;
        float a = g[c] * rsqrtf(var + EPSF);
        CF[s * 128 + c] = a;
        CF[s * 128 + 64 + c] = be[c] - mean * a;
    }
    __syncthreads();

    const _Float16* Ykh = Yk + ((size_t)h * RTOT + row0) * 8;
    const _Float16* Vrh = Vr + (size_t)h * RT9 + (size_t)(row0 >> 3) * 72;
    const _Float16* Yqh = Yq + ((size_t)h * RTOT + row0) * 8;

    // K: BN + row-major LDS
    {
        int m = tid;
        half8 y = *(const half8*)(Ykh + m * 8);
        half8 kv;
#pragma unroll
        for (int c = 0; c < 8; c++)
            kv[c] = (_Float16)fmaxf(CF[128 + co + c] * (float)y[c] + CF[192 + co + c], 0.f);
        *(half8*)&KL[m * 8] = kv;
    }
    // V: uint4 copy + per-uint4 BN (c = idx mod 9; c==8 is the ones column)
    for (int i = tid; i < 576; i += 512) {
        half8 v = ((const half8*)Vrh)[i];
        int c = i % 9;
        if (c < 8) {
            float a = CF[256 + co + c], b = CF[320 + co + c];
#pragma unroll
            for (int e = 0; e < 8; e++)
                v[e] = (_Float16)fmaxf(a * (float)v[e] + b, 0.f);
        }
        ((half8*)VS)[i] = v;
    }
    __syncthreads();

    int wv = tid >> 6;           // 0..7
    int lane = tid & 63;
    int ln = lane & 31;
    int hi = lane >> 5;

    f32x16 zacc, m12;
#pragma unroll
    for (int r = 0; r < 16; r++) { zacc[r] = 0.f; m12[r] = -12.f; }
    half8 hzero;
#pragma unroll
    for (int i = 0; i < 8; i++) hzero[i] = (_Float16)0.f;

#pragma unroll
    for (int sstep = 0; sstep < 2; sstep++) {
        int si = wv + 8 * sstep;
        int n0 = si * 32;
        half8 qf = hzero;
        if (!hi) {
            half8 y = *(const half8*)(Yqh + (n0 + ln) * 8);
            float zmv = (float)zt[(size_t)h * RTOT + row0 + n0 + ln];
#pragma unroll
            for (int c = 0; c < 8; c++)
                qf[c] = (_Float16)(fmaxf(CF[co + c] * (float)y[c] + CF[64 + co + c], 0.f) * zmv);
        }
        f32x16 acc = zacc;

#pragma unroll 4
        for (int t = 0; t < 16; t++) {
            half8 kf = hzero;
            if (!hi) kf = *(const half8*)&KL[(t * 32 + ln) * 8];
            f32x16 sv = __builtin_amdgcn_mfma_f32_32x32x16_f16(kf, qf, m12, 0, 0, 0);
            float pe[16];
#pragma unroll
            for (int r = 0; r < 16; r++)
                pe[r] = __builtin_amdgcn_exp2f(sv[r]);
#pragma unroll
            for (int ks = 0; ks < 2; ks++) {
                unsigned int x1 = bcu(cvt2h(pe[8*ks+0], pe[8*ks+1]));
                unsigned int x2 = bcu(cvt2h(pe[8*ks+2], pe[8*ks+3]));
                unsigned int y1 = bcu(cvt2h(pe[8*ks+4], pe[8*ks+5]));
                unsigned int y2 = bcu(cvt2h(pe[8*ks+6], pe[8*ks+7]));
                swap32(x1, y1, hi);
                swap32(x2, y2, hi);
                uint4 pw = make_uint4(x1, x2, y1, y2);
                half8 pa = __builtin_bit_cast(half8, pw);
                int chunk = t * 4 + ks * 2 + hi;
                half8 vf = hzero;
                if (ln <= 8) vf = *(const half8*)&VS[chunk * 72 + ln * 8];
                acc = __builtin_amdgcn_mfma_f32_32x32x16_f16(pa, vf, acc, 0, 0, 0);
            }
        }

        // epilogue -> LDS (c=8 lane holds the softmax denominator)
#pragma unroll
        for (int r = 0; r < 16; r++) {
            float av = acc[r];
            float den = __shfl(av, 8 + 32 * hi, 64);
            float ov = av * __builtin_amdgcn_rcpf(den);
            if (ln < 8) {
                int nrow = n0 + (r & 3) + 8 * (r >> 2) + 4 * hi;
                OL[nrow * 8 + ln] = (_Float16)ov;
            }
        }
    }
    __syncthreads();
    ((uint4*)(O + ((size_t)h * RTOT + row0) * 8))[tid] = ((const uint4*)OL)[tid];
}

// ---------------------------------------------------------------------------
// Cooperative (192 blocks, proven R7-R10): O-projection GEMM (head-major X) +
// stats + grid.sync + BN-ReLU -> d_out. Accumulators live across the sync.
// ---------------------------------------------------------------------------
__global__ __launch_bounds__(256) void gemm_o_norm(
        const _Float16* __restrict__ X,
        const float* __restrict__ Wo, const float* __restrict__ bo,
        const float* __restrict__ go, const float* __restrict__ betao,
        float* __restrict__ st, float* __restrict__ out) {
    __shared__ char WT[8192];
    __shared__ float red[128];
    __shared__ float CF[128];
    int tid = threadIdx.x;
    for (int i = tid; i < 4096; i += 256) {
        int d = i >> 6, e = i & 63;
        int off = ((e * 64 + d) * 2) ^ ((e & 7) << 4);
        *(_Float16*)(&WT[off]) = (_Float16)Wo[i];
    }
    if (tid < 128) red[tid] = 0.f;

    int wvi = tid >> 6, lane = tid & 63, ln = lane & 31, hi = lane >> 5;
    int rbase = blockIdx.x * 256 + wvi * 64;

    half8 af[2][4];
#pragma unroll
    for (int rt = 0; rt < 2; rt++)
#pragma unroll
        for (int kc = 0; kc < 4; kc++)
            af[rt][kc] = *(const half8*)(X + ((size_t)(2*kc + hi) * RTOT + rbase + rt*32 + ln) * 8);
    __syncthreads();

    half8 bf[2][4];
#pragma unroll
    for (int ct = 0; ct < 2; ct++)
#pragma unroll
        for (int kc = 0; kc < 4; kc++) {
            int e = ct * 32 + ln;
            int off = ((e * 64 + kc * 16 + 8 * hi) * 2) ^ ((e & 7) << 4);
            bf[ct][kc] = *(const half8*)(&WT[off]);
        }

    f32x16 acc[2][2];
#pragma unroll
    for (int rt = 0; rt < 2; rt++)
#pragma unroll
        for (int ct = 0; ct < 2; ct++) {
#pragma unroll
            for (int r = 0; r < 16; r++) acc[rt][ct][r] = 0.f;
#pragma unroll
            for (int kc = 0; kc < 4; kc++)
                acc[rt][ct] = __builtin_amdgcn_mfma_f32_32x32x16_f16(
                    af[rt][kc], bf[ct][kc], acc[rt][ct], 0, 0, 0);
        }

#pragma unroll
    for (int ct = 0; ct < 2; ct++) {
        float bv_ = bo[ct * 32 + ln];
        float s = 0.f, q = 0.f;
#pragma unroll
        for (int rt = 0; rt < 2; rt++)
#pragma unroll
            for (int r = 0; r < 16; r++) {
                float v = acc[rt][ct][r] + bv_;
                acc[rt][ct][r] = v;
                s += v; q += v * v;
            }
        s += __shfl_xor(s, 32, 64);
        q += __shfl_xor(q, 32, 64);
        if (lane < 32) {
            atomicAdd(&red[ct*32 + ln], s);
            atomicAdd(&red[64 + ct*32 + ln], q);
        }
    }
    __syncthreads();
    if (tid < 128) atomicAdd(&st[tid], red[tid]);

    __threadfence();
    cooperative_groups::this_grid().sync();

    if (tid < 64) {
        float inv = 1.f / (float)RTOT;
        float mean = st[tid] * inv;
        float var  = st[64 + tid] * inv - mean * mean;
        float a = go[tid] * rsqrtf(var + EPSF);
        CF[tid] = a;
        CF[64 + tid] = betao[tid] - mean * a;
    }
    __syncthreads();

#pragma unroll
    for (int ct = 0; ct < 2; ct++) {
        int c = ct * 32 + ln;
        float a = CF[c], b = CF[64 + c];
#pragma unroll
        for (int rt = 0; rt < 2; rt++)
#pragma unroll
            for (int r = 0; r < 16; r++) {
                int row = rbase + rt*32 + (r & 3) + 8*(r >> 2) + 4*hi;
                out[(size_t)row * 64 + c] = fmaxf(a * acc[rt][ct][r] + b, 0.f);
            }
    }
}

extern "C" void kernel_launch(void* const* d_in, const int* in_sizes, int n_in,
                              void* d_out, int out_size, void* d_ws, size_t ws_size,
                              hipStream_t stream) {
    const float* Q    = (const float*)d_in[0];
    const float* Kin  = (const float*)d_in[1];
    const float* mask = (const float*)d_in[2];
    const float* Wq = (const float*)d_in[4];
    const float* bq = (const float*)d_in[5];
    const float* gq = (const float*)d_in[6];
    const float* betaq = (const float*)d_in[7];
    const float* Wk = (const float*)d_in[8];
    const float* bk = (const float*)d_in[9];
    const float* gk = (const float*)d_in[10];
    const float* betak = (const float*)d_in[11];
    const float* Wv = (const float*)d_in[12];
    const float* bv = (const float*)d_in[13];
    const float* gv = (const float*)d_in[14];
    const float* betav = (const float*)d_in[15];
    const float* Wo = (const float*)d_in[16];
    const float* bo = (const float*)d_in[17];
    const float* go = (const float*)d_in[18];
    const float* betao = (const float*)d_in[19];

    const size_t TSZ = (size_t)RTOT * 64;
    _Float16* Yq = (_Float16*)d_ws;               // raw head-major
    _Float16* Yk = Yq + TSZ;
    _Float16* Vr = Yk + TSZ;                      // raw pre-interleaved, RTOT*72
    _Float16* Ob = Vr + (size_t)RTOT * 72;
    _Float16* zt = Ob + TSZ;                      // 8 * RTOT halfs
    float* stats = (float*)(zt + (size_t)8 * RTOT);  // 512 floats

    (void)hipMemsetAsync(stats, 0, 512 * sizeof(float), stream);

    dim3 gqkv(192, 3);
    gemm_qkv<<<gqkv, 256, 0, stream>>>(Q, Kin, mask, Wq, bq, Wk, bk, Wv, bv,
                                       Yq, Yk, Vr, zt, stats);

    attn_mfma<<<768, 512, 0, stream>>>(Yq, Yk, Vr, zt, stats,
                                       gq, betaq, gk, betak, gv, betav, Ob);

    {
        const _Float16* Xo = Ob;
        float* st4 = stats + 384;
        float* outp = (float*)d_out;
        void* args[] = { (void*)&Xo, (void*)&Wo, (void*)&bo,
                         (void*)&go, (void*)&betao, (void*)&st4, (void*)&outp };
        (void)hipLaunchCooperativeKernel(reinterpret_cast<void*>(&gemm_o_norm),
                                         dim3(192), dim3(256), args, 0, stream);
    }
}